// Round 7
// baseline (22.358 us; speedup 1.0000x reference)
//
#include <hip/hip_runtime.h>

// SpanRepresentation: B=16, L=128, D=768, W=128, SPAN_MAX_LEN=8 -> n_spans=996
// out = spans (B,996,1664) f32 ++ span_indices (996,2) as float, flat.
//
// R5: source-centric scatter (1 x-load -> 16 contiguous 1KB wave-stores),
//     width-major groups make hi/hj segments contiguous copies of x.
// R6: uniform per-XCD unit grid — each XCD runs an identical self-contained
//     list of {heavy x-scatter, fw-broadcast, idx} wave-units, removing the
//     heavy-then-light dispatch tail of R5.

#define LSEQ   128
#define DDIM   768
#define NSPANS 996
#define ROW    1664
#define PER_B  ((long)NSPANS * ROW)   // floats per batch in spans output

#define UNITS_HEAVY 768               // per XCD: 2 batches * 128 rows * 3 chunks
#define UNITS_FW    996               // per XCD: 2*996*32 f4 / 64 lanes
#define UNITS_IDX   4                 // per XCD: covers 256 idx-f4 (8*256 >= 498)
#define UNITS_PER_XCD (UNITS_HEAVY + UNITS_FW + UNITS_IDX)   // 1768
#define BLOCKS_PER_XCD (UNITS_PER_XCD / 4)                   // 442
#define FW_PER_XCD  63744             // 2*996*32 f4
#define FW_PER_B    31872             // 996*32 f4
#define IDX4        498
#define SPANS_FLOATS ((long)16 * PER_B)

typedef float f4 __attribute__((ext_vector_type(4)));

__device__ __forceinline__ int bucket_of_span(int s) {
    int w = 1;
    if (s >= 128) w = 2;
    if (s >= 255) w = 3;
    if (s >= 381) w = 4;
    if (s >= 506) w = 5;
    if (s >= 630) w = 6;
    if (s >= 753) w = 7;
    if (s >= 875) w = 8;
    return w - (w >= 6 ? 1 : 0);
}

__device__ __forceinline__ void start_end_of_span(int s, int& start, int& end) {
    int w = 1, base = 0;
    if (s >= 128) { w = 2; base = 128; }
    if (s >= 255) { w = 3; base = 255; }
    if (s >= 381) { w = 4; base = 381; }
    if (s >= 506) { w = 5; base = 506; }
    if (s >= 630) { w = 6; base = 630; }
    if (s >= 753) { w = 7; base = 753; }
    if (s >= 875) { w = 8; base = 875; }
    start = s - base;
    end   = start + w - 1;
}

__global__ __launch_bounds__(256) void span_rep_kernel(
        const float* __restrict__ x,
        const float* __restrict__ we,
        float* __restrict__ out) {
    const int wg   = blockIdx.x;
    const int xcd  = wg & 7;                  // XCD slab: batches {2*xcd, 2*xcd+1}
    const int ublk = wg >> 3;                 // [0, BLOCKS_PER_XCD)
    const int wave = threadIdx.x >> 6;
    const int lane = threadIdx.x & 63;
    const int unit = ublk * 4 + wave;         // [0, UNITS_PER_XCD), wave-uniform

    if (unit < UNITS_HEAVY) {
        // ---- heavy: one x float4 -> up to 16 contiguous 1KB wave-stores ----
        const int half = (unit >= 384) ? 1 : 0;
        const int b    = 2 * xcd + half;
        const int r    = unit - half * 384;   // [0,384)
        const int s    = r / 3;               // source row, wave-uniform
        const int q    = r - s * 3;           // 64-f4 chunk of the 192-f4 row
        const int c    = (q * 64 + lane) * 4; // [0,768) float col

        const f4 v = *reinterpret_cast<const f4*>(
            &x[((long)b * LSEQ + s) * DDIM + c]);

        float* ob = out + (long)b * PER_B;

        #pragma unroll
        for (int w = 1; w <= 8; ++w) {
            const int base = (w==1)?0:(w==2)?128:(w==3)?255:(w==4)?381:
                             (w==5)?506:(w==6)?630:(w==7)?753:875;
            if (s <= LSEQ - w)    // hi of span row base+s
                *reinterpret_cast<f4*>(&ob[(long)(base + s) * ROW + c]) = v;
            if (s >= w - 1)       // hj of span row base+s-w+1
                *reinterpret_cast<f4*>(&ob[(long)(base + s - w + 1) * ROW + DDIM + c]) = v;
        }
    } else if (unit < UNITS_HEAVY + UNITS_FW) {
        // ---- fw: width-embedding broadcast for this slab's 2 batches ----
        const int fidx = (unit - UNITS_HEAVY) * 64 + lane;   // [0, FW_PER_XCD)
        const int half = (fidx >= FW_PER_B) ? 1 : 0;
        const int b    = 2 * xcd + half;
        const int rem  = fidx - half * FW_PER_B;             // [0, FW_PER_B)
        const int sIdx = rem >> 5;                           // span row
        const int c4f  = rem & 31;                           // f4 within fw seg
        const int bucket = bucket_of_span(sIdx);
        const f4 v = *reinterpret_cast<const f4*>(&we[bucket * 128 + c4f * 4]);
        *reinterpret_cast<f4*>(
            &out[(long)b * PER_B + (long)sIdx * ROW + 2 * DDIM + c4f * 4]) = v;
    } else {
        // ---- idx tail: 8 XCDs x 4 units x 64 lanes = 2048 slots >= 498 ----
        const int k = (xcd * UNITS_IDX + (unit - UNITS_HEAVY - UNITS_FW)) * 64 + lane;
        if (k < IDX4) {
            int st0, en0, st1, en1;
            start_end_of_span(2 * k,     st0, en0);
            start_end_of_span(2 * k + 1, st1, en1);
            f4 v = { (float)st0, (float)en0, (float)st1, (float)en1 };
            *reinterpret_cast<f4*>(&out[SPANS_FLOATS + (long)k * 4]) = v;
        }
    }
}

extern "C" void kernel_launch(void* const* d_in, const int* in_sizes, int n_in,
                              void* d_out, int out_size, void* d_ws, size_t ws_size,
                              hipStream_t stream) {
    const float* x  = (const float*)d_in[0];
    const float* we = (const float*)d_in[1];
    float* out = (float*)d_out;

    span_rep_kernel<<<8 * BLOCKS_PER_XCD, 256, 0, stream>>>(x, we, out);
}